// Round 2
// baseline (625.988 us; speedup 1.0000x reference)
//
#include <hip/hip_runtime.h>
#include <hip/hip_fp16.h>
#include <stdint.h>

// Problem: x[16,2048,512] f32, embed[4096,512] f32.
// encode: idx[n] = argmax_k -(||x_n||^2 - 2 x_n.e_k + ||e_k||^2)  (== argmax x.e - 0.5*||e||^2)
// decode: quantize[n] = embed[idx[n]]
// d_out (float): [0,32768) = idx as float, [32768, 32768+32768*512) = quantize.

typedef _Float16 f16;
typedef __attribute__((ext_vector_type(4))) _Float16 f16x4;
typedef __attribute__((ext_vector_type(8))) _Float16 f16x8;
typedef __attribute__((ext_vector_type(4))) float f32x4;

#define DDIM 512
#define KCODES 4096
#define NSPLIT 4
#define BM 128
#define BN 128
#define BK 32
#define PSTRIDE (NSPLIT * 2)  // per-row partial slots: (nsp, wc)

__device__ __forceinline__ void gload_lds16(const void* g, void* l) {
  __builtin_amdgcn_global_load_lds(
      (const __attribute__((address_space(1))) void*)g,
      (__attribute__((address_space(3))) void*)l,
      16, 0, 0);
}

// -------- conversion: f32 -> (hi f16, lo f16), 4 elems/thread, grid-stride ----
__global__ void convert_split(const float* __restrict__ in,
                              f16* __restrict__ hi, f16* __restrict__ lo, int n4) {
  int stride = gridDim.x * blockDim.x;
  for (int i = blockIdx.x * blockDim.x + threadIdx.x; i < n4; i += stride) {
    float4 v = ((const float4*)in)[i];
    float vv[4] = {v.x, v.y, v.z, v.w};
    f16x4 h, l;
#pragma unroll
    for (int j = 0; j < 4; ++j) {
      _Float16 hh = (_Float16)vv[j];
      h[j] = hh;
      l[j] = (_Float16)(vv[j] - (float)hh);
    }
    ((f16x4*)hi)[i] = h;
    ((f16x4*)lo)[i] = l;
  }
}

// -------- e_sq: one wave per code row, f64 accumulation ----------------------
__global__ void esq_kernel(const float* __restrict__ e, float* __restrict__ esq) {
  int gw = (blockIdx.x * blockDim.x + threadIdx.x) >> 6;
  int lane = threadIdx.x & 63;
  if (gw >= KCODES) return;
  const float4* row = (const float4*)(e + (size_t)gw * DDIM);
  float4 a = row[lane * 2];
  float4 b = row[lane * 2 + 1];
  double s = (double)a.x * a.x + (double)a.y * a.y + (double)a.z * a.z + (double)a.w * a.w +
             (double)b.x * b.x + (double)b.y * b.y + (double)b.z * b.z + (double)b.w * b.w;
#pragma unroll
  for (int m = 32; m; m >>= 1) s += __shfl_xor(s, m, 64);
  if (lane == 0) esq[gw] = (float)s;
}

// -------- main: fused 3-pass f16 GEMM + running argmax -----------------------
// grid = (nRows/BM) * NSPLIT blocks, 256 threads (4 waves, 2x2 wave grid, 64x64/wave)
__global__ __launch_bounds__(256) void vq_main(
    const f16* __restrict__ Ah, const f16* __restrict__ Al,
    const f16* __restrict__ Bh, const f16* __restrict__ Bl,
    const float* __restrict__ esq, float2* __restrict__ partials, int nRowBlocks) {
  __shared__ f16 Als[BM * BK];  // 8 KiB, row-major [row][32]
  __shared__ f16 Bls[BN * BK];  // 8 KiB, row-major [code][32]

  int nwg = gridDim.x;
  int bid = blockIdx.x;
  int cpx = nwg >> 3;                       // nwg % 8 == 0
  int swz = (bid & 7) * cpx + (bid >> 3);   // XCD-aware swizzle
  int nsp = swz / nRowBlocks;
  int brow = swz % nRowBlocks;
  int rowbase = brow * BM;

  int tid = threadIdx.x;
  int lane = tid & 63;
  int wv = tid >> 6;
  int wr = wv >> 1, wc = wv & 1;
  int l15 = lane & 15, lg = lane >> 4;

  // ds_read fragment byte offsets (row stride = 64 B)
  const int aoff = (wr * 64 + l15) * 64 + lg * 16;
  const int boff = (wc * 64 + l15) * 64 + lg * 16;
  char* AlsB = (char*)Als;
  char* BlsB = (char*)Bls;
  char* ldsA0 = AlsB + wv * 1024;  // wave-uniform staging dest
  char* ldsB0 = BlsB + wv * 1024;

  int srow = tid >> 2;          // staging row within 64-row half
  int skoff = (tid & 3) * 8;    // f16 element offset within row

  float bestv[16];
  int besti[16];
#pragma unroll
  for (int t = 0; t < 16; ++t) { bestv[t] = -3.4e38f; besti[t] = 0; }

  const int codesPer = KCODES / NSPLIT;  // 1024
  for (int ch = 0; ch < codesPer / BN; ++ch) {
    int cbase = nsp * codesPer + ch * BN;
    f32x4 acc[4][4];
#pragma unroll
    for (int i = 0; i < 4; ++i)
#pragma unroll
      for (int j = 0; j < 4; ++j) acc[i][j] = (f32x4){0.f, 0.f, 0.f, 0.f};

#pragma unroll 1
    for (int pass = 0; pass < 3; ++pass) {
      const f16* Ap = (pass == 2) ? Al : Ah;   // hi, hi, lo
      const f16* Bp = (pass == 1) ? Bl : Bh;   // hi, lo, hi
      const f16* aSrc = Ap + (size_t)(rowbase + srow) * DDIM + skoff;
      const f16* bSrc = Bp + (size_t)(cbase + srow) * DDIM + skoff;
#pragma unroll 1
      for (int kk = 0; kk < DDIM; kk += BK) {
        gload_lds16(aSrc + kk, ldsA0);
        gload_lds16(aSrc + (size_t)64 * DDIM + kk, ldsA0 + 4096);
        gload_lds16(bSrc + kk, ldsB0);
        gload_lds16(bSrc + (size_t)64 * DDIM + kk, ldsB0 + 4096);
        __syncthreads();
        f16x8 af[4], bf[4];
#pragma unroll
        for (int i = 0; i < 4; ++i) af[i] = *(const f16x8*)(AlsB + aoff + i * 1024);
#pragma unroll
        for (int j = 0; j < 4; ++j) bf[j] = *(const f16x8*)(BlsB + boff + j * 1024);
#pragma unroll
        for (int i = 0; i < 4; ++i)
#pragma unroll
          for (int j = 0; j < 4; ++j)
            acc[i][j] = __builtin_amdgcn_mfma_f32_16x16x32_f16(af[i], bf[j], acc[i][j], 0, 0, 0);
        __syncthreads();
      }
    }

    // epilogue: val = dot - 0.5*esq (monotone-equivalent to -(x_sq - 2*dot + e_sq))
#pragma unroll
    for (int j = 0; j < 4; ++j) {
      int code = cbase + wc * 64 + j * 16 + l15;
      float eh = 0.5f * esq[code];
#pragma unroll
      for (int i = 0; i < 4; ++i)
#pragma unroll
        for (int r = 0; r < 4; ++r) {
          float v = acc[i][j][r] - eh;
          int t = i * 4 + r;
          if (v > bestv[t]) { bestv[t] = v; besti[t] = code; }
        }
    }
  }

  // butterfly over the 16 lanes (l15) holding different codes of the same rows
#pragma unroll
  for (int m = 1; m < 16; m <<= 1) {
#pragma unroll
    for (int t = 0; t < 16; ++t) {
      float ov = __shfl_xor(bestv[t], m, 64);
      int oi = __shfl_xor(besti[t], m, 64);
      if (ov > bestv[t] || (ov == bestv[t] && oi < besti[t])) { bestv[t] = ov; besti[t] = oi; }
    }
  }
  // each (row, nsp, wc) gets its own partial slot — waves wc=0/1 cover
  // different 64-code halves of the tile and must NOT share a slot.
  if (l15 == 0) {
#pragma unroll
    for (int i = 0; i < 4; ++i)
#pragma unroll
      for (int r = 0; r < 4; ++r) {
        int row = rowbase + wr * 64 + i * 16 + lg * 4 + r;
        partials[(size_t)row * PSTRIDE + nsp * 2 + wc] =
            make_float2(bestv[i * 4 + r], (float)besti[i * 4 + r]);
      }
  }
}

// -------- reduce over PSTRIDE partials + decode gather -----------------------
__global__ void reduce_decode(const float* __restrict__ embed,
                              const float2* __restrict__ partials,
                              float* __restrict__ outIdx, float* __restrict__ outQ,
                              int nRows) {
  int gw = (blockIdx.x * blockDim.x + threadIdx.x) >> 6;
  int lane = threadIdx.x & 63;
  if (gw >= nRows) return;
  float bv = -3.4e38f;
  int bi = 0x7fffffff;
#pragma unroll
  for (int s = 0; s < PSTRIDE; ++s) {
    float2 p = partials[(size_t)gw * PSTRIDE + s];
    int idx = (int)p.y;
    if (p.x > bv || (p.x == bv && idx < bi)) { bv = p.x; bi = idx; }
  }
  if (lane == 0) outIdx[gw] = (float)bi;
  const float4* src = (const float4*)(embed + (size_t)bi * DDIM);
  float4* dst = (float4*)(outQ + (size_t)gw * DDIM);
  dst[lane] = src[lane];
  dst[lane + 64] = src[lane + 64];
}

extern "C" void kernel_launch(void* const* d_in, const int* in_sizes, int n_in,
                              void* d_out, int out_size, void* d_ws, size_t ws_size,
                              hipStream_t stream) {
  const float* x = (const float*)d_in[0];
  const float* embed = (const float*)d_in[1];
  int nX = in_sizes[0];        // 16*2048*512
  int nRows = nX / DDIM;       // 32768
  int nRowBlocks = nRows / BM; // 256

  float* out = (float*)d_out;
  float* outIdx = out;
  float* outQ = out + nRows;

  size_t szA = (size_t)nRows * DDIM * sizeof(f16);   // 32 MiB
  size_t szB = (size_t)KCODES * DDIM * sizeof(f16);  // 4 MiB
  size_t szEsq = (size_t)KCODES * sizeof(float);
  size_t szPart = (size_t)nRows * PSTRIDE * sizeof(float2);  // 2 MiB

  char* ws = (char*)d_ws;
  f16 *Ah, *Al, *Bh, *Bl;
  float* esq;
  float2* parts;
  size_t needFull = 2 * szA + 2 * szB + szEsq + szPart;
  if (ws_size >= needFull) {
    Ah = (f16*)ws;
    Al = (f16*)(ws + szA);
    Bh = (f16*)(ws + 2 * szA);
    Bl = (f16*)(ws + 2 * szA + szB);
    esq = (float*)(ws + 2 * szA + 2 * szB);
    parts = (float2*)(ws + 2 * szA + 2 * szB + szEsq);
  } else {
    // quantize region of d_out (64 MiB) exactly fits Ah+Al; overwritten by decode at the end
    Ah = (f16*)outQ;
    Al = Ah + (size_t)nRows * DDIM;
    Bh = (f16*)ws;
    Bl = (f16*)(ws + szB);
    esq = (float*)(ws + 2 * szB);
    parts = (float2*)(ws + 2 * szB + szEsq);
  }

  int n4x = nX / 4;
  int n4e = in_sizes[1] / 4;
  hipLaunchKernelGGL(convert_split, dim3(2048), dim3(256), 0, stream, x, Ah, Al, n4x);
  hipLaunchKernelGGL(convert_split, dim3((n4e + 255) / 256), dim3(256), 0, stream, embed, Bh, Bl, n4e);
  hipLaunchKernelGGL(esq_kernel, dim3(KCODES / 4), dim3(256), 0, stream, embed, esq);
  hipLaunchKernelGGL(vq_main, dim3(nRowBlocks * NSPLIT), dim3(256), 0, stream,
                     Ah, Al, Bh, Bl, esq, parts, nRowBlocks);
  hipLaunchKernelGGL(reduce_decode, dim3(nRows / 4), dim3(256), 0, stream,
                     embed, parts, outIdx, outQ, nRows);
}

// Round 3
// 416.939 us; speedup vs baseline: 1.5014x; 1.5014x over previous
//
#include <hip/hip_runtime.h>
#include <hip/hip_fp16.h>
#include <stdint.h>

// Problem: x[16,2048,512] f32, embed[4096,512] f32.
// encode: idx[n] = argmax_k -(||x_n||^2 - 2 x_n.e_k + ||e_k||^2)  (== argmax x.e - 0.5*||e||^2)
// decode: quantize[n] = embed[idx[n]]
// d_out (float): [0,32768) = idx as float, [32768, +32768*512) = quantize.
//
// Split-f16 exact-enough GEMM: x = xh + xl (f16 each), dot = xh.eh + xh.el + xl.eh
// (lo.lo term ~6e-6 << min top-2 gap). All 3 combos computed per LDS staging.

typedef _Float16 f16;
typedef __attribute__((ext_vector_type(4))) _Float16 f16x4;
typedef __attribute__((ext_vector_type(8))) _Float16 f16x8;
typedef __attribute__((ext_vector_type(4))) float f32x4;

#define DDIM 512
#define KCODES 4096
#define NSPLIT 4
#define BM 128
#define BN 256
#define BK 32
#define PSTRIDE (NSPLIT * 2)  // per-row partial slots: (nsp, wc)

__device__ __forceinline__ void gload_lds16(const void* g, void* l) {
  __builtin_amdgcn_global_load_lds(
      (const __attribute__((address_space(1))) void*)g,
      (__attribute__((address_space(3))) void*)l,
      16, 0, 0);
}

// -------- conversion: f32 -> (hi f16, lo f16), 4 elems/thread, grid-stride ----
__global__ void convert_split(const float* __restrict__ in,
                              f16* __restrict__ hi, f16* __restrict__ lo, int n4) {
  int stride = gridDim.x * blockDim.x;
  for (int i = blockIdx.x * blockDim.x + threadIdx.x; i < n4; i += stride) {
    float4 v = ((const float4*)in)[i];
    float vv[4] = {v.x, v.y, v.z, v.w};
    f16x4 h, l;
#pragma unroll
    for (int j = 0; j < 4; ++j) {
      _Float16 hh = (_Float16)vv[j];
      h[j] = hh;
      l[j] = (_Float16)(vv[j] - (float)hh);
    }
    ((f16x4*)hi)[i] = h;
    ((f16x4*)lo)[i] = l;
  }
}

// -------- e_sq: one wave per code row, f64 accumulation ----------------------
__global__ void esq_kernel(const float* __restrict__ e, float* __restrict__ esq) {
  int gw = (blockIdx.x * blockDim.x + threadIdx.x) >> 6;
  int lane = threadIdx.x & 63;
  if (gw >= KCODES) return;
  const float4* row = (const float4*)(e + (size_t)gw * DDIM);
  float4 a = row[lane * 2];
  float4 b = row[lane * 2 + 1];
  double s = (double)a.x * a.x + (double)a.y * a.y + (double)a.z * a.z + (double)a.w * a.w +
             (double)b.x * b.x + (double)b.y * b.y + (double)b.z * b.z + (double)b.w * b.w;
#pragma unroll
  for (int m = 32; m; m >>= 1) s += __shfl_xor(s, m, 64);
  if (lane == 0) esq[gw] = (float)s;
}

// -------- main: fused 3-combo f16 GEMM + running argmax ----------------------
// grid = (nRows/BM) * NSPLIT = 1024 blocks, 256 threads (4 waves, 2x2 grid,
// wave tile = 64 rows x 128 codes, acc[4][8]). LDS 48 KiB: Ah,Al[128][32] +
// Bh,Bl[256][32]. All four sub-tiles staged once per K-step; 48 MFMA/barrier.
__global__ __launch_bounds__(256, 2) void vq_main(
    const f16* __restrict__ Ah, const f16* __restrict__ Al,
    const f16* __restrict__ Bh, const f16* __restrict__ Bl,
    const float* __restrict__ esq, float2* __restrict__ partials, int nRowBlocks) {
  __shared__ f16 lds[24576];  // 48 KiB
  char* const AhB = (char*)lds;          // [128][32] f16, 8 KiB
  char* const AlB = AhB + 8192;          // 8 KiB
  char* const BhB = AhB + 16384;         // [256][32] f16, 16 KiB
  char* const BlB = AhB + 32768;         // 16 KiB

  int nwg = gridDim.x;
  int bid = blockIdx.x;
  int cpx = nwg >> 3;                       // nwg % 8 == 0
  int swz = (bid & 7) * cpx + (bid >> 3);   // XCD-aware swizzle (bijective)
  int nsp = swz / nRowBlocks;
  int brow = swz % nRowBlocks;
  int rowbase = brow * BM;

  int tid = threadIdx.x;
  int lane = tid & 63;
  int wv = tid >> 6;
  int wr = wv >> 1, wc = wv & 1;
  int l15 = lane & 15, lg = lane >> 4;

  // fragment byte offsets (row stride = 64 B)
  const int aoff = (wr * 64 + l15) * 64 + lg * 16;
  const int boff = (wc * 128 + l15) * 64 + lg * 16;
  char* const stA = AhB + wv * 1024;  // wave-uniform staging dests
  char* const stB = BhB + wv * 1024;

  int srow = tid >> 2;          // staging row (4 threads/row, 64 rows/round)
  int skoff = (tid & 3) * 8;    // f16 element offset within row

  float bestv[16];
  int besti[16];
#pragma unroll
  for (int t = 0; t < 16; ++t) { bestv[t] = -3.4e38f; besti[t] = 0; }

  const int codesPer = KCODES / NSPLIT;  // 1024
  const f16* aSrcH = Ah + (size_t)(rowbase + srow) * DDIM + skoff;
  const f16* aSrcL = Al + (size_t)(rowbase + srow) * DDIM + skoff;

  for (int ch = 0; ch < codesPer / BN; ++ch) {  // 4 chunks of 256 codes
    int cbase = nsp * codesPer + ch * BN;
    const f16* bSrcH = Bh + (size_t)(cbase + srow) * DDIM + skoff;
    const f16* bSrcL = Bl + (size_t)(cbase + srow) * DDIM + skoff;

    f32x4 acc[4][8];
#pragma unroll
    for (int i = 0; i < 4; ++i)
#pragma unroll
      for (int j = 0; j < 8; ++j) acc[i][j] = (f32x4){0.f, 0.f, 0.f, 0.f};

#pragma unroll 1
    for (int kk = 0; kk < DDIM; kk += BK) {
      // stage Ah, Al (2 rounds each) and Bh, Bl (4 rounds each): 48 KiB
      gload_lds16(aSrcH + kk, stA);
      gload_lds16(aSrcH + (size_t)64 * DDIM + kk, stA + 4096);
      gload_lds16(aSrcL + kk, stA + 8192);
      gload_lds16(aSrcL + (size_t)64 * DDIM + kk, stA + 8192 + 4096);
#pragma unroll
      for (int r = 0; r < 4; ++r) {
        gload_lds16(bSrcH + (size_t)(r * 64) * DDIM + kk, stB + r * 4096);
        gload_lds16(bSrcL + (size_t)(r * 64) * DDIM + kk, stB + 16384 + r * 4096);
      }
      __syncthreads();

      f16x8 ah[4], al[4], bh[8], bl[8];
#pragma unroll
      for (int i = 0; i < 4; ++i) ah[i] = *(const f16x8*)(AhB + aoff + i * 1024);
#pragma unroll
      for (int j = 0; j < 8; ++j) bh[j] = *(const f16x8*)(BhB + boff + j * 1024);
#pragma unroll
      for (int i = 0; i < 4; ++i)
#pragma unroll
        for (int j = 0; j < 8; ++j)
          acc[i][j] = __builtin_amdgcn_mfma_f32_16x16x32_f16(ah[i], bh[j], acc[i][j], 0, 0, 0);
#pragma unroll
      for (int i = 0; i < 4; ++i) al[i] = *(const f16x8*)(AlB + aoff + i * 1024);
#pragma unroll
      for (int i = 0; i < 4; ++i)
#pragma unroll
        for (int j = 0; j < 8; ++j)
          acc[i][j] = __builtin_amdgcn_mfma_f32_16x16x32_f16(al[i], bh[j], acc[i][j], 0, 0, 0);
#pragma unroll
      for (int j = 0; j < 8; ++j) bl[j] = *(const f16x8*)(BlB + boff + j * 1024);
#pragma unroll
      for (int i = 0; i < 4; ++i)
#pragma unroll
        for (int j = 0; j < 8; ++j)
          acc[i][j] = __builtin_amdgcn_mfma_f32_16x16x32_f16(ah[i], bl[j], acc[i][j], 0, 0, 0);
      __syncthreads();
    }

    // epilogue: val = dot - 0.5*esq (monotone-equivalent to ref dist)
#pragma unroll
    for (int j = 0; j < 8; ++j) {
      int code = cbase + wc * 128 + j * 16 + l15;
      float eh = 0.5f * esq[code];
#pragma unroll
      for (int i = 0; i < 4; ++i)
#pragma unroll
        for (int r = 0; r < 4; ++r) {
          float v = acc[i][j][r] - eh;
          int t = i * 4 + r;
          if (v > bestv[t]) { bestv[t] = v; besti[t] = code; }
        }
    }
  }

  // butterfly over the 16 lanes (l15) holding different codes of the same rows
#pragma unroll
  for (int m = 1; m < 16; m <<= 1) {
#pragma unroll
    for (int t = 0; t < 16; ++t) {
      float ov = __shfl_xor(bestv[t], m, 64);
      int oi = __shfl_xor(besti[t], m, 64);
      if (ov > bestv[t] || (ov == bestv[t] && oi < besti[t])) { bestv[t] = ov; besti[t] = oi; }
    }
  }
  // unique slot per (row, nsp, wc)
  if (l15 == 0) {
#pragma unroll
    for (int i = 0; i < 4; ++i)
#pragma unroll
      for (int r = 0; r < 4; ++r) {
        int row = rowbase + wr * 64 + i * 16 + lg * 4 + r;
        partials[(size_t)row * PSTRIDE + nsp * 2 + wc] =
            make_float2(bestv[i * 4 + r], (float)besti[i * 4 + r]);
      }
  }
}

// -------- reduce over PSTRIDE partials + decode gather -----------------------
__global__ void reduce_decode(const float* __restrict__ embed,
                              const float2* __restrict__ partials,
                              float* __restrict__ outIdx, float* __restrict__ outQ,
                              int nRows) {
  int gw = (blockIdx.x * blockDim.x + threadIdx.x) >> 6;
  int lane = threadIdx.x & 63;
  if (gw >= nRows) return;
  float bv = -3.4e38f;
  int bi = 0x7fffffff;
#pragma unroll
  for (int s = 0; s < PSTRIDE; ++s) {
    float2 p = partials[(size_t)gw * PSTRIDE + s];
    int idx = (int)p.y;
    if (p.x > bv || (p.x == bv && idx < bi)) { bv = p.x; bi = idx; }
  }
  if (lane == 0) outIdx[gw] = (float)bi;
  const float4* src = (const float4*)(embed + (size_t)bi * DDIM);
  float4* dst = (float4*)(outQ + (size_t)gw * DDIM);
  dst[lane] = src[lane];
  dst[lane + 64] = src[lane + 64];
}

extern "C" void kernel_launch(void* const* d_in, const int* in_sizes, int n_in,
                              void* d_out, int out_size, void* d_ws, size_t ws_size,
                              hipStream_t stream) {
  const float* x = (const float*)d_in[0];
  const float* embed = (const float*)d_in[1];
  int nX = in_sizes[0];        // 16*2048*512
  int nRows = nX / DDIM;       // 32768
  int nRowBlocks = nRows / BM; // 256

  float* out = (float*)d_out;
  float* outIdx = out;
  float* outQ = out + nRows;

  size_t szA = (size_t)nRows * DDIM * sizeof(f16);   // 32 MiB
  size_t szB = (size_t)KCODES * DDIM * sizeof(f16);  // 4 MiB
  size_t szEsq = (size_t)KCODES * sizeof(float);
  size_t szPart = (size_t)nRows * PSTRIDE * sizeof(float2);  // 2 MiB

  char* ws = (char*)d_ws;
  f16 *Ah, *Al, *Bh, *Bl;
  float* esq;
  float2* parts;
  size_t needFull = 2 * szA + 2 * szB + szEsq + szPart;
  if (ws_size >= needFull) {
    Ah = (f16*)ws;
    Al = (f16*)(ws + szA);
    Bh = (f16*)(ws + 2 * szA);
    Bl = (f16*)(ws + 2 * szA + szB);
    esq = (float*)(ws + 2 * szA + 2 * szB);
    parts = (float2*)(ws + 2 * szA + 2 * szB + szEsq);
  } else {
    // quantize region of d_out (64 MiB) exactly fits Ah+Al; overwritten by decode at the end
    Ah = (f16*)outQ;
    Al = Ah + (size_t)nRows * DDIM;
    Bh = (f16*)ws;
    Bl = (f16*)(ws + szB);
    esq = (float*)(ws + 2 * szB);
    parts = (float2*)(ws + 2 * szB + szEsq);
  }

  int n4x = nX / 4;
  int n4e = in_sizes[1] / 4;
  hipLaunchKernelGGL(convert_split, dim3(2048), dim3(256), 0, stream, x, Ah, Al, n4x);
  hipLaunchKernelGGL(convert_split, dim3((n4e + 255) / 256), dim3(256), 0, stream, embed, Bh, Bl, n4e);
  hipLaunchKernelGGL(esq_kernel, dim3(KCODES / 4), dim3(256), 0, stream, embed, esq);
  hipLaunchKernelGGL(vq_main, dim3(nRowBlocks * NSPLIT), dim3(256), 0, stream,
                     Ah, Al, Bh, Bl, esq, parts, nRowBlocks);
  hipLaunchKernelGGL(reduce_decode, dim3(nRows / 4), dim3(256), 0, stream,
                     embed, parts, outIdx, outQ, nRows);
}

// Round 4
// 379.430 us; speedup vs baseline: 1.6498x; 1.0989x over previous
//
#include <hip/hip_runtime.h>
#include <hip/hip_fp16.h>
#include <stdint.h>

// Problem: x[16,2048,512] f32, embed[4096,512] f32.
// encode: idx[n] = argmax_k -(||x_n||^2 - 2 x_n.e_k + ||e_k||^2)  (== argmax x.e - 0.5*||e||^2)
// decode: quantize[n] = embed[idx[n]]
// d_out (float): [0,32768) = idx as float, [32768, +32768*512) = quantize.
//
// Split-f16 GEMM: x = xh + xl, dot = xh.eh + xl.eh + xh.el (lo.lo ~6e-6 negligible).
// vq_main: 256x256 tile, 512 thr (8 waves, 4x2), 2-phase double-buffered LDS
// (128 KiB), one __syncthreads per K-step, drain-at-end (loads age one full
// MFMA phase before the drain -> free).

typedef _Float16 f16;
typedef __attribute__((ext_vector_type(4))) _Float16 f16x4;
typedef __attribute__((ext_vector_type(8))) _Float16 f16x8;
typedef __attribute__((ext_vector_type(4))) float f32x4;

#define DDIM 512
#define KCODES 4096
#define NSPLIT 2
#define BM 256
#define BN 256
#define BK 32
#define NCH ((KCODES / NSPLIT) / BN)   // 8 chunks per block
#define NSTEPS (NCH * (DDIM / BK))     // 128 pipeline steps
#define PSTRIDE (NSPLIT * 2)           // per-row partial slots: (nsp, wc)

__device__ __forceinline__ void gload_lds16(const void* g, void* l) {
  __builtin_amdgcn_global_load_lds(
      (const __attribute__((address_space(1))) void*)g,
      (__attribute__((address_space(3))) void*)l,
      16, 0, 0);
}

// -------- conversion: f32 -> (hi f16, lo f16), 4 elems/thread, grid-stride ----
__global__ void convert_split(const float* __restrict__ in,
                              f16* __restrict__ hi, f16* __restrict__ lo, int n4) {
  int stride = gridDim.x * blockDim.x;
  for (int i = blockIdx.x * blockDim.x + threadIdx.x; i < n4; i += stride) {
    float4 v = ((const float4*)in)[i];
    float vv[4] = {v.x, v.y, v.z, v.w};
    f16x4 h, l;
#pragma unroll
    for (int j = 0; j < 4; ++j) {
      _Float16 hh = (_Float16)vv[j];
      h[j] = hh;
      l[j] = (_Float16)(vv[j] - (float)hh);
    }
    ((f16x4*)hi)[i] = h;
    ((f16x4*)lo)[i] = l;
  }
}

// -------- e_sq: one wave per code row, f64 accumulation ----------------------
__global__ void esq_kernel(const float* __restrict__ e, float* __restrict__ esq) {
  int gw = (blockIdx.x * blockDim.x + threadIdx.x) >> 6;
  int lane = threadIdx.x & 63;
  if (gw >= KCODES) return;
  const float4* row = (const float4*)(e + (size_t)gw * DDIM);
  float4 a = row[lane * 2];
  float4 b = row[lane * 2 + 1];
  double s = (double)a.x * a.x + (double)a.y * a.y + (double)a.z * a.z + (double)a.w * a.w +
             (double)b.x * b.x + (double)b.y * b.y + (double)b.z * b.z + (double)b.w * b.w;
#pragma unroll
  for (int m = 32; m; m >>= 1) s += __shfl_xor(s, m, 64);
  if (lane == 0) esq[gw] = (float)s;
}

// -------- main: 2-phase pipelined 3-combo f16 GEMM + running argmax ----------
// grid = (nRows/256) * NSPLIT = 256 blocks (1/CU), 512 threads.
// LDS layout per buffer (64 KiB): Ah[256][32] @0, Al @16384, Bh @32768, Bl @49152.
__global__ __launch_bounds__(512, 2) void vq_main(
    const f16* __restrict__ Ah, const f16* __restrict__ Al,
    const f16* __restrict__ Bh, const f16* __restrict__ Bl,
    const float* __restrict__ esq, float2* __restrict__ partials, int nRowBlocks) {
  __shared__ char lds[131072];  // 2 x 64 KiB double buffer

  int nwg = gridDim.x;
  int bid = blockIdx.x;
  int cpx = nwg >> 3;                       // nwg % 8 == 0
  int swz = (bid & 7) * cpx + (bid >> 3);   // XCD-aware swizzle (bijective)
  int nsp = swz / nRowBlocks;
  int brow = swz % nRowBlocks;
  int rowbase = brow * BM;

  int tid = threadIdx.x;
  int lane = tid & 63;
  int wv = tid >> 6;        // 0..7 waves, 4 (rows) x 2 (codes)
  int wr = wv >> 1, wc = wv & 1;
  int l15 = lane & 15, lg = lane >> 4;

  // fragment byte offsets within a sub-region (row stride 64 B): conflict-free
  const int aoff = (wr * 64 + l15) * 64 + lg * 16;
  const int boff = (wc * 128 + l15) * 64 + lg * 16;

  int srow = tid >> 2;          // staging row (4 threads/row, 128 rows/round)
  int skoff = (tid & 3) * 8;    // f16 element offset within row
  const int codesPer = KCODES / NSPLIT;  // 2048

  const f16* aSrcH = Ah + (size_t)(rowbase + srow) * DDIM + skoff;
  const f16* aSrcL = Al + (size_t)(rowbase + srow) * DDIM + skoff;
  const f16* bBaseH = Bh + (size_t)(nsp * codesPer + srow) * DDIM + skoff;
  const f16* bBaseL = Bl + (size_t)(nsp * codesPer + srow) * DDIM + skoff;

  auto STAGE = [&](int buf, int ch, int kk) {
    char* base = lds + buf * 65536 + wv * 1024;  // + lane*16 added by HW
    size_t bo = (size_t)(ch * BN) * DDIM + kk;
    gload_lds16(aSrcH + kk, base);
    gload_lds16(aSrcH + kk + (size_t)128 * DDIM, base + 8192);
    gload_lds16(aSrcL + kk, base + 16384);
    gload_lds16(aSrcL + kk + (size_t)128 * DDIM, base + 16384 + 8192);
    gload_lds16(bBaseH + bo, base + 32768);
    gload_lds16(bBaseH + bo + (size_t)128 * DDIM, base + 32768 + 8192);
    gload_lds16(bBaseL + bo, base + 49152);
    gload_lds16(bBaseL + bo + (size_t)128 * DDIM, base + 49152 + 8192);
  };

  float bestv[16];
  int besti[16];
#pragma unroll
  for (int t = 0; t < 16; ++t) { bestv[t] = -3.4e38f; besti[t] = 0; }

  f32x4 acc[4][8];

  STAGE(0, 0, 0);
  __syncthreads();

  int buf = 0;
#pragma unroll 1
  for (int s = 0; s < NSTEPS; ++s) {
    int ch = s >> 4;
    // issue next step's loads first (they age through the MFMA phase)
    int ns = s + 1;
    if (ns < NSTEPS) STAGE(buf ^ 1, ns >> 4, (ns & 15) * BK);

    if ((s & 15) == 0) {
#pragma unroll
      for (int i = 0; i < 4; ++i)
#pragma unroll
        for (int j = 0; j < 8; ++j) acc[i][j] = (f32x4){0.f, 0.f, 0.f, 0.f};
    }

    char* base = lds + buf * 65536;
    f16x8 ah[4], al[4], bh[8], bl[8];
#pragma unroll
    for (int i = 0; i < 4; ++i) ah[i] = *(const f16x8*)(base + aoff + i * 1024);
#pragma unroll
    for (int j = 0; j < 8; ++j) bh[j] = *(const f16x8*)(base + 32768 + boff + j * 1024);
#pragma unroll
    for (int i = 0; i < 4; ++i)
#pragma unroll
      for (int j = 0; j < 8; ++j)
        acc[i][j] = __builtin_amdgcn_mfma_f32_16x16x32_f16(ah[i], bh[j], acc[i][j], 0, 0, 0);
#pragma unroll
    for (int i = 0; i < 4; ++i) al[i] = *(const f16x8*)(base + 16384 + aoff + i * 1024);
#pragma unroll
    for (int i = 0; i < 4; ++i)
#pragma unroll
      for (int j = 0; j < 8; ++j)
        acc[i][j] = __builtin_amdgcn_mfma_f32_16x16x32_f16(al[i], bh[j], acc[i][j], 0, 0, 0);
#pragma unroll
    for (int j = 0; j < 8; ++j) bl[j] = *(const f16x8*)(base + 49152 + boff + j * 1024);
#pragma unroll
    for (int i = 0; i < 4; ++i)
#pragma unroll
      for (int j = 0; j < 8; ++j)
        acc[i][j] = __builtin_amdgcn_mfma_f32_16x16x32_f16(ah[i], bl[j], acc[i][j], 0, 0, 0);

    if ((s & 15) == 15) {
      // chunk epilogue: registers + global esq only (no LDS) — safe pre-barrier
      int cbase = nsp * codesPer + ch * BN;
#pragma unroll
      for (int j = 0; j < 8; ++j) {
        int code = cbase + wc * 128 + j * 16 + l15;
        float eh = 0.5f * esq[code];
#pragma unroll
        for (int i = 0; i < 4; ++i)
#pragma unroll
          for (int r = 0; r < 4; ++r) {
            float v = acc[i][j][r] - eh;
            int t = i * 4 + r;
            if (v > bestv[t]) { bestv[t] = v; besti[t] = code; }
          }
      }
    }
    // one barrier per step: drains the (old) in-flight loads + protects the
    // buffer we just read from being overwritten by next step's STAGE.
    __syncthreads();
    buf ^= 1;
  }

  // butterfly over the 16 lanes (l15) holding different codes of the same rows
#pragma unroll
  for (int m = 1; m < 16; m <<= 1) {
#pragma unroll
    for (int t = 0; t < 16; ++t) {
      float ov = __shfl_xor(bestv[t], m, 64);
      int oi = __shfl_xor(besti[t], m, 64);
      if (ov > bestv[t] || (ov == bestv[t] && oi < besti[t])) { bestv[t] = ov; besti[t] = oi; }
    }
  }
  // unique slot per (row, nsp, wc)
  if (l15 == 0) {
#pragma unroll
    for (int i = 0; i < 4; ++i)
#pragma unroll
      for (int r = 0; r < 4; ++r) {
        int row = rowbase + wr * 64 + i * 16 + lg * 4 + r;
        partials[(size_t)row * PSTRIDE + nsp * 2 + wc] =
            make_float2(bestv[i * 4 + r], (float)besti[i * 4 + r]);
      }
  }
}

// -------- reduce over PSTRIDE partials + decode gather -----------------------
__global__ void reduce_decode(const float* __restrict__ embed,
                              const float2* __restrict__ partials,
                              float* __restrict__ outIdx, float* __restrict__ outQ,
                              int nRows) {
  int gw = (blockIdx.x * blockDim.x + threadIdx.x) >> 6;
  int lane = threadIdx.x & 63;
  if (gw >= nRows) return;
  float bv = -3.4e38f;
  int bi = 0x7fffffff;
#pragma unroll
  for (int s = 0; s < PSTRIDE; ++s) {
    float2 p = partials[(size_t)gw * PSTRIDE + s];
    int idx = (int)p.y;
    if (p.x > bv || (p.x == bv && idx < bi)) { bv = p.x; bi = idx; }
  }
  if (lane == 0) outIdx[gw] = (float)bi;
  const float4* src = (const float4*)(embed + (size_t)bi * DDIM);
  float4* dst = (float4*)(outQ + (size_t)gw * DDIM);
  dst[lane] = src[lane];
  dst[lane + 64] = src[lane + 64];
}

extern "C" void kernel_launch(void* const* d_in, const int* in_sizes, int n_in,
                              void* d_out, int out_size, void* d_ws, size_t ws_size,
                              hipStream_t stream) {
  const float* x = (const float*)d_in[0];
  const float* embed = (const float*)d_in[1];
  int nX = in_sizes[0];        // 16*2048*512
  int nRows = nX / DDIM;       // 32768
  int nRowBlocks = nRows / BM; // 128

  float* out = (float*)d_out;
  float* outIdx = out;
  float* outQ = out + nRows;

  size_t szA = (size_t)nRows * DDIM * sizeof(f16);   // 32 MiB
  size_t szB = (size_t)KCODES * DDIM * sizeof(f16);  // 4 MiB
  size_t szEsq = (size_t)KCODES * sizeof(float);
  size_t szPart = (size_t)nRows * PSTRIDE * sizeof(float2);  // 1 MiB

  char* ws = (char*)d_ws;
  f16 *Ah, *Al, *Bh, *Bl;
  float* esq;
  float2* parts;
  size_t needFull = 2 * szA + 2 * szB + szEsq + szPart;
  if (ws_size >= needFull) {
    Ah = (f16*)ws;
    Al = (f16*)(ws + szA);
    Bh = (f16*)(ws + 2 * szA);
    Bl = (f16*)(ws + 2 * szA + szB);
    esq = (float*)(ws + 2 * szA + 2 * szB);
    parts = (float2*)(ws + 2 * szA + 2 * szB + szEsq);
  } else {
    // quantize region of d_out (64 MiB) exactly fits Ah+Al; overwritten by decode at the end
    Ah = (f16*)outQ;
    Al = Ah + (size_t)nRows * DDIM;
    Bh = (f16*)ws;
    Bl = (f16*)(ws + szB);
    esq = (float*)(ws + 2 * szB);
    parts = (float2*)(ws + 2 * szB + szEsq);
  }

  int n4x = nX / 4;
  int n4e = in_sizes[1] / 4;
  hipLaunchKernelGGL(convert_split, dim3(2048), dim3(256), 0, stream, x, Ah, Al, n4x);
  hipLaunchKernelGGL(convert_split, dim3((n4e + 255) / 256), dim3(256), 0, stream, embed, Bh, Bl, n4e);
  hipLaunchKernelGGL(esq_kernel, dim3(KCODES / 4), dim3(256), 0, stream, embed, esq);
  hipLaunchKernelGGL(vq_main, dim3(nRowBlocks * NSPLIT), dim3(512), 0, stream,
                     Ah, Al, Bh, Bl, esq, parts, nRowBlocks);
  hipLaunchKernelGGL(reduce_decode, dim3(nRows / 4), dim3(256), 0, stream,
                     embed, parts, outIdx, outQ, nRows);
}